// Round 4
// baseline (95.901 us; speedup 1.0000x reference)
//
#include <hip/hip_runtime.h>

#define HH 512
#define WW 512
#define NIMG 16
#define SEG 2            // output rows per wave
#define EPSF 1e-5f
#define INV81 (1.0f / 81.0f)

// One wave per (image, 2-row strip); lane owns 8 consecutive x columns.
// 5 running column sums over the 9-row window (batched warm-up, then
// add y+4 / sub y-4 with loads issued ahead of dependent compute).
// Horizontal 9-box via lane+-1 shuffles + in-register sliding sum.
// Finalization fused: last block (atomic counter) writes d_out.
__global__ __launch_bounds__(256, 4) void ncc_main(const float* __restrict__ Iin,
                                                   const float* __restrict__ Jin,
                                                   double* __restrict__ acc,
                                                   unsigned* __restrict__ cnt,
                                                   float* __restrict__ out) {
    const int tid  = threadIdx.x;
    const int lane = tid & 63;
    const int gw   = blockIdx.x * 4 + (tid >> 6);   // global wave 0..4095
    const int n    = gw >> 8;                        // image (256 strips each)
    const int y0   = (gw & 255) * SEG;
    const int x0   = lane << 3;                      // 8 columns per lane

    const float* Ib = Iin + (size_t)n * (HH * WW) + x0;
    const float* Jb = Jin + (size_t)n * (HH * WW) + x0;

    float CI[8], CJ[8], CI2[8], CJ2[8], CIJ[8];
    #pragma unroll
    for (int c = 0; c < 8; ++c) { CI[c] = 0.f; CJ[c] = 0.f; CI2[c] = 0.f; CJ2[c] = 0.f; CIJ[c] = 0.f; }

    auto loadrow = [&](int r, float (&a)[8], float (&b)[8]) {
        const float4* pI = (const float4*)(Ib + (size_t)r * WW);
        const float4* pJ = (const float4*)(Jb + (size_t)r * WW);
        float4 aL = pI[0], aH = pI[1];
        float4 bL = pJ[0], bH = pJ[1];
        a[0]=aL.x; a[1]=aL.y; a[2]=aL.z; a[3]=aL.w; a[4]=aH.x; a[5]=aH.y; a[6]=aH.z; a[7]=aH.w;
        b[0]=bL.x; b[1]=bL.y; b[2]=bL.z; b[3]=bL.w; b[4]=bH.x; b[5]=bH.y; b[6]=bH.z; b[7]=bH.w;
    };
    auto zerorow = [&](float (&a)[8], float (&b)[8]) {
        #pragma unroll
        for (int c = 0; c < 8; ++c) { a[c] = 0.f; b[c] = 0.f; }
    };
    auto addrow = [&](const float (&a)[8], const float (&b)[8]) {
        #pragma unroll
        for (int c = 0; c < 8; ++c) {
            CI[c] += a[c];  CJ[c] += b[c];
            CI2[c] = fmaf(a[c], a[c], CI2[c]);
            CJ2[c] = fmaf(b[c], b[c], CJ2[c]);
            CIJ[c] = fmaf(a[c], b[c], CIJ[c]);
        }
    };
    auto subrow = [&](const float (&a)[8], const float (&b)[8]) {
        #pragma unroll
        for (int c = 0; c < 8; ++c) {
            CI[c] -= a[c];  CJ[c] -= b[c];
            CI2[c] = fmaf(-a[c], a[c], CI2[c]);
            CJ2[c] = fmaf(-b[c], b[c], CJ2[c]);
            CIJ[c] = fmaf(-a[c], b[c], CIJ[c]);
        }
    };

    // Batched warm-up: rows y0-4..y0-1 and y0..y0+3 (wave-uniform validity)
    auto warm4 = [&](int r0) {
        float A[4][8], B[4][8];
        #pragma unroll
        for (int k = 0; k < 4; ++k) {
            const int r = r0 + k;
            if (r >= 0 && r < HH) loadrow(r, A[k], B[k]);
            else                  zerorow(A[k], B[k]);
        }
        #pragma unroll
        for (int k = 0; k < 4; ++k) addrow(A[k], B[k]);
    };
    warm4(y0 - 4);
    warm4(y0);

    const bool L0  = (lane == 0);
    const bool L63 = (lane == 63);

    auto hbox = [&](const float (&C)[8], float (&B)[8]) {
        float H[16];
        #pragma unroll
        for (int k = 0; k < 4; ++k) {
            float l = __shfl_up(C[4 + k], 1);
            H[k] = L0 ? 0.f : l;
        }
        #pragma unroll
        for (int k = 0; k < 8; ++k) H[4 + k] = C[k];
        #pragma unroll
        for (int k = 0; k < 4; ++k) {
            float r = __shfl_down(C[k], 1);
            H[12 + k] = L63 ? 0.f : r;
        }
        float s = ((H[0] + H[1]) + (H[2] + H[3])) + ((H[4] + H[5]) + (H[6] + H[7])) + H[8];
        B[0] = s;
        #pragma unroll
        for (int i = 1; i < 8; ++i) { s += H[i + 8] - H[i - 1]; B[i] = s; }
    };

    float local = 0.f;
    auto ccrow = [&]() {
        float BI[8], BJ[8], BI2[8], BJ2[8], BIJ[8];
        hbox(CI, BI); hbox(CJ, BJ); hbox(CI2, BI2); hbox(CJ2, BJ2); hbox(CIJ, BIJ);
        #pragma unroll
        for (int c = 0; c < 8; ++c) {
            const float tI = BI[c] * INV81;
            const float tJ = BJ[c] * INV81;
            const float cross = fmaf(-tI, BJ[c], BIJ[c]);
            const float Iv    = fmaf(-tI, BI[c], BI2[c]);
            const float Jv    = fmaf(-tJ, BJ[c], BJ2[c]);
            const float den   = fmaf(Iv, Jv, EPSF);
            local = fmaf(cross * cross, __builtin_amdgcn_rcpf(den), local);
        }
    };

    // Main: 2 output rows. Loads issued ahead of dependent compute.
    const bool av0 = (y0 + 4 < HH), av1 = (y0 + 5 < HH), sv = (y0 >= 4);

    float A0[8], B0[8], S0a[8], S0b[8];
    if (av0) loadrow(y0 + 4, A0, B0); else zerorow(A0, B0);
    if (sv)  loadrow(y0 - 4, S0a, S0b); else zerorow(S0a, S0b);
    addrow(A0, B0);
    subrow(S0a, S0b);

    float A1[8], B1[8], S1a[8], S1b[8];          // issue before row-y0 compute
    if (av1) loadrow(y0 + 5, A1, B1); else zerorow(A1, B1);
    if (sv)  loadrow(y0 - 3, S1a, S1b); else zerorow(S1a, S1b);

    ccrow();                                      // output row y0

    addrow(A1, B1);
    subrow(S1a, S1b);
    ccrow();                                      // output row y0+1

    // wave reduction, block reduction, one atomic per block; last block finalizes
    #pragma unroll
    for (int off = 32; off > 0; off >>= 1) local += __shfl_down(local, off);
    __shared__ float wsum[4];
    if (lane == 0) wsum[tid >> 6] = local;
    __syncthreads();
    if (tid == 0) {
        atomicAdd(acc, (double)(wsum[0] + wsum[1] + wsum[2] + wsum[3]));
        __threadfence();
        const unsigned old = atomicAdd(cnt, 1u);
        if (old == gridDim.x - 1) {
            const double t = atomicAdd(acc, 0.0);   // coherent read of final sum
            out[0] = 1.0f - (float)(t * (1.0 / (double)((size_t)NIMG * HH * WW)));
        }
    }
}

extern "C" void kernel_launch(void* const* d_in, const int* in_sizes, int n_in,
                              void* d_out, int out_size, void* d_ws, size_t ws_size,
                              hipStream_t stream) {
    const float* I = (const float*)d_in[0];
    const float* J = (const float*)d_in[1];
    float* out = (float*)d_out;
    double* acc = (double*)d_ws;
    unsigned* cnt = (unsigned*)((char*)d_ws + 8);

    hipMemsetAsync(d_ws, 0, 16, stream);
    // 4096 waves = 16 images x 256 strips of 2 rows; 4 waves/block, 1024 blocks
    // = exactly 4 blocks/CU on 256 CUs (zero tail)
    ncc_main<<<1024, 256, 0, stream>>>(I, J, acc, cnt, out);
}

// Round 6
// 60.222 us; speedup vs baseline: 1.5924x; 1.5924x over previous
//
#include <hip/hip_runtime.h>

#define HH 512
#define WW 512
#define NIMG 16
#define SEG 2            // output rows per wave
#define EPSF 1e-5f
#define INV81 (1.0f / 81.0f)

// One wave per (image, 2-row strip); lane owns 8 consecutive x columns.
// 5 running column sums over the 9-row window: warm-up one row at a time
// (low live-set, no spills), then per output row: add y+4, compute cc,
// subtract y-4 (ORDER MATTERS: sub after cc). Horizontal 9-box via
// lane+-1 shuffles + in-register sliding sum. Whole row = one wave ->
// no LDS for data, no barriers. Last block (atomic counter) finalizes.
__global__ __launch_bounds__(256, 3) void ncc_main(const float* __restrict__ Iin,
                                                   const float* __restrict__ Jin,
                                                   double* __restrict__ acc,
                                                   unsigned* __restrict__ cnt,
                                                   float* __restrict__ out) {
    const int tid  = threadIdx.x;
    const int lane = tid & 63;
    const int gw   = blockIdx.x * 4 + (tid >> 6);   // global wave 0..4095
    const int n    = gw >> 8;                        // image (256 strips each)
    const int y0   = (gw & 255) * SEG;
    const int x0   = lane << 3;                      // 8 columns per lane

    const float* Ib = Iin + (size_t)n * (HH * WW) + x0;
    const float* Jb = Jin + (size_t)n * (HH * WW) + x0;

    float CI[8], CJ[8], CI2[8], CJ2[8], CIJ[8];
    #pragma unroll
    for (int c = 0; c < 8; ++c) { CI[c] = 0.f; CJ[c] = 0.f; CI2[c] = 0.f; CJ2[c] = 0.f; CIJ[c] = 0.f; }

    auto loadrow = [&](int r, float (&a)[8], float (&b)[8]) {
        const float4* pI = (const float4*)(Ib + (size_t)r * WW);
        const float4* pJ = (const float4*)(Jb + (size_t)r * WW);
        float4 aL = pI[0], aH = pI[1];
        float4 bL = pJ[0], bH = pJ[1];
        a[0]=aL.x; a[1]=aL.y; a[2]=aL.z; a[3]=aL.w; a[4]=aH.x; a[5]=aH.y; a[6]=aH.z; a[7]=aH.w;
        b[0]=bL.x; b[1]=bL.y; b[2]=bL.z; b[3]=bL.w; b[4]=bH.x; b[5]=bH.y; b[6]=bH.z; b[7]=bH.w;
    };
    auto zerorow = [&](float (&a)[8], float (&b)[8]) {
        #pragma unroll
        for (int c = 0; c < 8; ++c) { a[c] = 0.f; b[c] = 0.f; }
    };
    auto addrow = [&](const float (&a)[8], const float (&b)[8]) {
        #pragma unroll
        for (int c = 0; c < 8; ++c) {
            CI[c] += a[c];  CJ[c] += b[c];
            CI2[c] = fmaf(a[c], a[c], CI2[c]);
            CJ2[c] = fmaf(b[c], b[c], CJ2[c]);
            CIJ[c] = fmaf(a[c], b[c], CIJ[c]);
        }
    };
    auto subrow = [&](const float (&a)[8], const float (&b)[8]) {
        #pragma unroll
        for (int c = 0; c < 8; ++c) {
            CI[c] -= a[c];  CJ[c] -= b[c];
            CI2[c] = fmaf(-a[c], a[c], CI2[c]);
            CJ2[c] = fmaf(-b[c], b[c], CJ2[c]);
            CIJ[c] = fmaf(-a[c], b[c], CIJ[c]);
        }
    };

    // Warm-up: rows y0-4 .. y0+3, one row at a time (keeps live-set small).
    // MUST clip both ends: with SEG=2, y0+3 can reach 513 (OOB + wrong math).
    #pragma unroll 1
    for (int r = y0 - 4; r <= y0 + 3; ++r) {
        if (r < 0 || r >= HH) continue;               // wave-uniform
        float a[8], b[8];
        loadrow(r, a, b);
        addrow(a, b);
    }

    const bool L0  = (lane == 0);
    const bool L63 = (lane == 63);

    auto hbox = [&](const float (&C)[8], float (&B)[8]) {
        float H[16];
        #pragma unroll
        for (int k = 0; k < 4; ++k) {
            float l = __shfl_up(C[4 + k], 1);
            H[k] = L0 ? 0.f : l;
        }
        #pragma unroll
        for (int k = 0; k < 8; ++k) H[4 + k] = C[k];
        #pragma unroll
        for (int k = 0; k < 4; ++k) {
            float r = __shfl_down(C[k], 1);
            H[12 + k] = L63 ? 0.f : r;
        }
        float s = ((H[0] + H[1]) + (H[2] + H[3])) + ((H[4] + H[5]) + (H[6] + H[7])) + H[8];
        B[0] = s;
        #pragma unroll
        for (int i = 1; i < 8; ++i) { s += H[i + 8] - H[i - 1]; B[i] = s; }
    };

    float local = 0.f;
    auto ccrow = [&]() {
        float BI[8], BJ[8], BI2[8], BJ2[8], BIJ[8];
        hbox(CI, BI); hbox(CJ, BJ); hbox(CI2, BI2); hbox(CJ2, BJ2); hbox(CIJ, BIJ);
        #pragma unroll
        for (int c = 0; c < 8; ++c) {
            const float tI = BI[c] * INV81;
            const float tJ = BJ[c] * INV81;
            const float cross = fmaf(-tI, BJ[c], BIJ[c]);
            const float Iv    = fmaf(-tI, BI[c], BI2[c]);
            const float Jv    = fmaf(-tJ, BJ[c], BJ2[c]);
            const float den   = fmaf(Iv, Jv, EPSF);
            local = fmaf(cross * cross, __builtin_amdgcn_rcpf(den), local);
        }
    };

    #pragma unroll 1
    for (int i = 0; i < SEG; ++i) {
        const int y = y0 + i;

        // issue both loads up-front: sub-row latency hidden under ccrow
        float aN[8], bN[8], aO[8], bO[8];
        const bool addv = (y + 4 < HH);               // wave-uniform
        const bool subv = (y >= 4);
        if (addv) loadrow(y + 4, aN, bN); else zerorow(aN, bN);
        if (subv) loadrow(y - 4, aO, bO); else zerorow(aO, bO);

        addrow(aN, bN);   // window now rows y-4..y+4
        ccrow();          // output row y
        subrow(aO, bO);   // drop row y-4 for next iteration
    }

    // wave reduction, block reduction, one atomic per block; last block finalizes
    #pragma unroll
    for (int off = 32; off > 0; off >>= 1) local += __shfl_down(local, off);
    __shared__ float wsum[4];
    if (lane == 0) wsum[tid >> 6] = local;
    __syncthreads();
    if (tid == 0) {
        atomicAdd(acc, (double)(wsum[0] + wsum[1] + wsum[2] + wsum[3]));
        __threadfence();
        const unsigned old = atomicAdd(cnt, 1u);
        if (old == gridDim.x - 1) {
            const double t = atomicAdd(acc, 0.0);     // coherent read of final sum
            out[0] = 1.0f - (float)(t * (1.0 / (double)((size_t)NIMG * HH * WW)));
        }
    }
}

extern "C" void kernel_launch(void* const* d_in, const int* in_sizes, int n_in,
                              void* d_out, int out_size, void* d_ws, size_t ws_size,
                              hipStream_t stream) {
    const float* I = (const float*)d_in[0];
    const float* J = (const float*)d_in[1];
    float* out = (float*)d_out;
    double* acc = (double*)d_ws;
    unsigned* cnt = (unsigned*)((char*)d_ws + 8);

    hipMemsetAsync(d_ws, 0, 16, stream);
    // 4096 waves = 16 images x 256 strips of 2 rows; 4 waves/block, 1024 blocks
    // = exactly 4 blocks/CU on 256 CUs (zero tail)
    ncc_main<<<1024, 256, 0, stream>>>(I, J, acc, cnt, out);
}

// Round 7
// 58.397 us; speedup vs baseline: 1.6422x; 1.0313x over previous
//
#include <hip/hip_runtime.h>

#define HH 512
#define WW 512
#define NIMG 16
#define EPSF 1e-5f
#define INV81 (1.0f / 81.0f)

// One wave per (image, 2-row strip); lane owns 8 consecutive x columns.
// NO rolling/warm-up chain: all 10 needed rows (y0-4..y0+5) are loaded as
// independent ping-pong pairs and accumulated into the 9-row column-sum
// window. cc(y0), then -row(y0-4)+row(y0+5), cc(y0+1). Horizontal 9-box
// via lane+-1 shuffles + in-register sliding sum. Last block finalizes.
__global__ __launch_bounds__(256, 3) void ncc_main(const float* __restrict__ Iin,
                                                   const float* __restrict__ Jin,
                                                   double* __restrict__ acc,
                                                   unsigned* __restrict__ cnt,
                                                   float* __restrict__ out) {
    const int tid  = threadIdx.x;
    const int lane = tid & 63;
    const int gw   = blockIdx.x * 4 + (tid >> 6);   // global wave 0..4095
    const int n    = gw >> 8;                        // image (256 strips each)
    const int y0   = (gw & 255) * 2;                 // first output row
    const int x0   = lane << 3;                      // 8 columns per lane

    const float* Ib = Iin + (size_t)n * (HH * WW) + x0;
    const float* Jb = Jin + (size_t)n * (HH * WW) + x0;

    float CI[8], CJ[8], CI2[8], CJ2[8], CIJ[8];
    #pragma unroll
    for (int c = 0; c < 8; ++c) { CI[c] = 0.f; CJ[c] = 0.f; CI2[c] = 0.f; CJ2[c] = 0.f; CIJ[c] = 0.f; }

    // load row r (clipped to zero outside [0,HH)) — validity is wave-uniform
    auto lz = [&](int r, float (&a)[8], float (&b)[8]) {
        if (r >= 0 && r < HH) {
            const float4* pI = (const float4*)(Ib + (size_t)r * WW);
            const float4* pJ = (const float4*)(Jb + (size_t)r * WW);
            float4 aL = pI[0], aH = pI[1];
            float4 bL = pJ[0], bH = pJ[1];
            a[0]=aL.x; a[1]=aL.y; a[2]=aL.z; a[3]=aL.w; a[4]=aH.x; a[5]=aH.y; a[6]=aH.z; a[7]=aH.w;
            b[0]=bL.x; b[1]=bL.y; b[2]=bL.z; b[3]=bL.w; b[4]=bH.x; b[5]=bH.y; b[6]=bH.z; b[7]=bH.w;
        } else {
            #pragma unroll
            for (int c = 0; c < 8; ++c) { a[c] = 0.f; b[c] = 0.f; }
        }
    };
    auto addrow = [&](const float (&a)[8], const float (&b)[8]) {
        #pragma unroll
        for (int c = 0; c < 8; ++c) {
            CI[c] += a[c];  CJ[c] += b[c];
            CI2[c] = fmaf(a[c], a[c], CI2[c]);
            CJ2[c] = fmaf(b[c], b[c], CJ2[c]);
            CIJ[c] = fmaf(a[c], b[c], CIJ[c]);
        }
    };
    auto subrow = [&](const float (&a)[8], const float (&b)[8]) {
        #pragma unroll
        for (int c = 0; c < 8; ++c) {
            CI[c] -= a[c];  CJ[c] -= b[c];
            CI2[c] = fmaf(-a[c], a[c], CI2[c]);
            CJ2[c] = fmaf(-b[c], b[c], CJ2[c]);
            CIJ[c] = fmaf(-a[c], b[c], CIJ[c]);
        }
    };

    // ---- load schedule: rm first, then 8 shared rows in ping-pong pairs ----
    float rma[8], rmb[8], rpa[8], rpb[8];
    float pa0[8], pb0[8], pa1[8], pb1[8];   // ping pair
    float qa0[8], qb0[8], qa1[8], qb1[8];   // pong pair

    lz(y0 - 4, rma, rmb);                     // row y0-4 (kept for the sub)
    lz(y0 - 3, pa0, pb0);  lz(y0 - 2, pa1, pb1);
    lz(y0 - 1, qa0, qb0);  lz(y0,     qa1, qb1);
    addrow(rma, rmb);
    addrow(pa0, pb0);      addrow(pa1, pb1);
    lz(y0 + 1, pa0, pb0);  lz(y0 + 2, pa1, pb1);
    addrow(qa0, qb0);      addrow(qa1, qb1);
    lz(y0 + 3, qa0, qb0);  lz(y0 + 4, qa1, qb1);
    addrow(pa0, pb0);      addrow(pa1, pb1);
    lz(y0 + 5, rpa, rpb);                     // row y0+5 (for second window)
    addrow(qa0, qb0);      addrow(qa1, qb1);
    // C now = rows y0-4 .. y0+4

    const bool L0  = (lane == 0);
    const bool L63 = (lane == 63);

    auto hbox = [&](const float (&C)[8], float (&B)[8]) {
        float H[16];
        #pragma unroll
        for (int k = 0; k < 4; ++k) {
            float l = __shfl_up(C[4 + k], 1);
            H[k] = L0 ? 0.f : l;
        }
        #pragma unroll
        for (int k = 0; k < 8; ++k) H[4 + k] = C[k];
        #pragma unroll
        for (int k = 0; k < 4; ++k) {
            float r = __shfl_down(C[k], 1);
            H[12 + k] = L63 ? 0.f : r;
        }
        float s = ((H[0] + H[1]) + (H[2] + H[3])) + ((H[4] + H[5]) + (H[6] + H[7])) + H[8];
        B[0] = s;
        #pragma unroll
        for (int i = 1; i < 8; ++i) { s += H[i + 8] - H[i - 1]; B[i] = s; }
    };

    float local = 0.f;
    auto ccrow = [&]() {
        float BI[8], BJ[8], BI2[8], BJ2[8], BIJ[8];
        hbox(CI, BI); hbox(CJ, BJ); hbox(CI2, BI2); hbox(CJ2, BJ2); hbox(CIJ, BIJ);
        #pragma unroll
        for (int c = 0; c < 8; ++c) {
            const float tI = BI[c] * INV81;
            const float tJ = BJ[c] * INV81;
            const float cross = fmaf(-tI, BJ[c], BIJ[c]);
            const float Iv    = fmaf(-tI, BI[c], BI2[c]);
            const float Jv    = fmaf(-tJ, BJ[c], BJ2[c]);
            const float den   = fmaf(Iv, Jv, EPSF);
            local = fmaf(cross * cross, __builtin_amdgcn_rcpf(den), local);
        }
    };

    ccrow();               // output row y0   (window rows y0-4..y0+4)
    subrow(rma, rmb);      // drop row y0-4
    addrow(rpa, rpb);      // add  row y0+5
    ccrow();               // output row y0+1 (window rows y0-3..y0+5)

    // wave reduction, block reduction, one atomic per block; last block finalizes
    #pragma unroll
    for (int off = 32; off > 0; off >>= 1) local += __shfl_down(local, off);
    __shared__ float wsum[4];
    if (lane == 0) wsum[tid >> 6] = local;
    __syncthreads();
    if (tid == 0) {
        atomicAdd(acc, (double)(wsum[0] + wsum[1] + wsum[2] + wsum[3]));
        __threadfence();
        const unsigned old = atomicAdd(cnt, 1u);
        if (old == gridDim.x - 1) {
            const double t = atomicAdd(acc, 0.0);     // coherent read of final sum
            out[0] = 1.0f - (float)(t * (1.0 / (double)((size_t)NIMG * HH * WW)));
        }
    }
}

extern "C" void kernel_launch(void* const* d_in, const int* in_sizes, int n_in,
                              void* d_out, int out_size, void* d_ws, size_t ws_size,
                              hipStream_t stream) {
    const float* I = (const float*)d_in[0];
    const float* J = (const float*)d_in[1];
    float* out = (float*)d_out;
    double* acc = (double*)d_ws;
    unsigned* cnt = (unsigned*)((char*)d_ws + 8);

    hipMemsetAsync(d_ws, 0, 16, stream);
    // 4096 waves = 16 images x 256 strips of 2 rows; 4 waves/block, 1024 blocks
    ncc_main<<<1024, 256, 0, stream>>>(I, J, acc, cnt, out);
}

// Round 8
// 34.704 us; speedup vs baseline: 2.7634x; 1.6827x over previous
//
#include <hip/hip_runtime.h>

#define HH 512
#define WW 512
#define NIMG 16
#define EPSF 1e-5f
#define INV81 (1.0f / 81.0f)

// Block = 4 waves, one (image, 16-row strip). LDS ring of 16 raw rows
// (I and J), each global row loaded ONCE per block. Wave w computes output
// rows y0+4s+w (s=0..3) by direct 9-row window sum from LDS (out-of-range
// rows stored as zeros -> no bounds logic on read). Horizontal 9-box via
// intra-wave shuffles (proven R3 code). One barrier per step: the write
// slot (rows +8..+11 mod 16) is never in any wave's current window.
__global__ __launch_bounds__(256, 2) void ncc_main(const float* __restrict__ Iin,
                                                   const float* __restrict__ Jin,
                                                   double* __restrict__ acc,
                                                   unsigned* __restrict__ cnt,
                                                   float* __restrict__ out) {
    __shared__ float ring[16][2][512];   // 64 KB: [slot][img][col]
    __shared__ float wsum[4];

    const int tid  = threadIdx.x;
    const int lane = tid & 63;
    const int w    = tid >> 6;           // wave id 0..3
    const int bid  = blockIdx.x;
    const int n    = bid >> 5;           // image (32 strips each)
    const int y0   = (bid & 31) << 4;    // strip base output row
    const int c0   = lane << 3;          // 8 cols per lane

    const float* Ib = Iin + (size_t)n * (HH * WW);
    const float* Jb = Jin + (size_t)n * (HH * WW);

    auto gload = [&](int r, float (&a)[8], float (&b)[8]) {
        if (r >= 0 && r < HH) {           // wave-uniform
            const float4* pI = (const float4*)(Ib + (size_t)r * WW + c0);
            const float4* pJ = (const float4*)(Jb + (size_t)r * WW + c0);
            float4 aL = pI[0], aH = pI[1], bL = pJ[0], bH = pJ[1];
            a[0]=aL.x; a[1]=aL.y; a[2]=aL.z; a[3]=aL.w; a[4]=aH.x; a[5]=aH.y; a[6]=aH.z; a[7]=aH.w;
            b[0]=bL.x; b[1]=bL.y; b[2]=bL.z; b[3]=bL.w; b[4]=bH.x; b[5]=bH.y; b[6]=bH.z; b[7]=bH.w;
        } else {
            #pragma unroll
            for (int c = 0; c < 8; ++c) { a[c] = 0.f; b[c] = 0.f; }
        }
    };
    auto swrite = [&](int r, const float (&a)[8], const float (&b)[8]) {
        const int sl = (r + 16) & 15;
        float4* dI = (float4*)&ring[sl][0][c0];
        float4* dJ = (float4*)&ring[sl][1][c0];
        dI[0] = make_float4(a[0], a[1], a[2], a[3]);
        dI[1] = make_float4(a[4], a[5], a[6], a[7]);
        dJ[0] = make_float4(b[0], b[1], b[2], b[3]);
        dJ[1] = make_float4(b[4], b[5], b[6], b[7]);
    };

    // Prologue: 12 rows (y0-4 .. y0+7), 3 per wave, all independent loads.
    {
        float a0[8], b0[8], a1[8], b1[8], a2[8], b2[8];
        gload(y0 - 4 + w, a0, b0);
        gload(y0     + w, a1, b1);
        gload(y0 + 4 + w, a2, b2);
        swrite(y0 - 4 + w, a0, b0);
        swrite(y0     + w, a1, b1);
        swrite(y0 + 4 + w, a2, b2);
    }
    __syncthreads();

    const bool L0  = (lane == 0);
    const bool L63 = (lane == 63);

    auto hbox = [&](const float (&C)[8], float (&B)[8]) {
        float H[16];
        #pragma unroll
        for (int k = 0; k < 4; ++k) {
            float l = __shfl_up(C[4 + k], 1);
            H[k] = L0 ? 0.f : l;
        }
        #pragma unroll
        for (int k = 0; k < 8; ++k) H[4 + k] = C[k];
        #pragma unroll
        for (int k = 0; k < 4; ++k) {
            float r = __shfl_down(C[k], 1);
            H[12 + k] = L63 ? 0.f : r;
        }
        float s = ((H[0] + H[1]) + (H[2] + H[3])) + ((H[4] + H[5]) + (H[6] + H[7])) + H[8];
        B[0] = s;
        #pragma unroll
        for (int i = 1; i < 8; ++i) { s += H[i + 8] - H[i - 1]; B[i] = s; }
    };

    float local = 0.f;

    #pragma unroll 1
    for (int s = 0; s < 4; ++s) {
        const int Y = y0 + 4 * s + w;     // this wave's output row

        // issue next global row early (latency hides under LDS compute)
        float na[8], nb[8];
        const int Rn = y0 + 4 * s + 8 + w;
        if (s < 3) gload(Rn, na, nb);

        // 9-row vertical window sums from LDS (zeros already stored for pads)
        float SI[8], SJ[8], SI2[8], SJ2[8], SIJ[8];
        #pragma unroll
        for (int c = 0; c < 8; ++c) { SI[c]=0.f; SJ[c]=0.f; SI2[c]=0.f; SJ2[c]=0.f; SIJ[c]=0.f; }
        #pragma unroll
        for (int k = 0; k < 9; ++k) {
            const int sl = (Y - 4 + k + 16) & 15;
            const float4* rI = (const float4*)&ring[sl][0][c0];
            const float4* rJ = (const float4*)&ring[sl][1][c0];
            float4 i0 = rI[0], i1 = rI[1], j0 = rJ[0], j1 = rJ[1];
            float ai[8] = {i0.x, i0.y, i0.z, i0.w, i1.x, i1.y, i1.z, i1.w};
            float bj[8] = {j0.x, j0.y, j0.z, j0.w, j1.x, j1.y, j1.z, j1.w};
            #pragma unroll
            for (int c = 0; c < 8; ++c) {
                SI[c] += ai[c];  SJ[c] += bj[c];
                SI2[c] = fmaf(ai[c], ai[c], SI2[c]);
                SJ2[c] = fmaf(bj[c], bj[c], SJ2[c]);
                SIJ[c] = fmaf(ai[c], bj[c], SIJ[c]);
            }
        }

        // horizontal 9-box + cc
        float BI[8], BJ[8], BI2[8], BJ2[8], BIJ[8];
        hbox(SI, BI); hbox(SJ, BJ); hbox(SI2, BI2); hbox(SJ2, BJ2); hbox(SIJ, BIJ);
        #pragma unroll
        for (int c = 0; c < 8; ++c) {
            const float tI = BI[c] * INV81;
            const float tJ = BJ[c] * INV81;
            const float cross = fmaf(-tI, BJ[c], BIJ[c]);
            const float Iv    = fmaf(-tI, BI[c], BI2[c]);
            const float Jv    = fmaf(-tJ, BJ[c], BJ2[c]);
            const float den   = fmaf(Iv, Jv, EPSF);
            local = fmaf(cross * cross, __builtin_amdgcn_rcpf(den), local);
        }

        // write next row: slot == rows (+8..+11) mod 16, outside all windows
        if (s < 3) swrite(Rn, na, nb);
        __syncthreads();
    }

    // wave reduction, block reduction, one atomic per block; last block finalizes
    #pragma unroll
    for (int off = 32; off > 0; off >>= 1) local += __shfl_down(local, off);
    if (lane == 0) wsum[w] = local;
    __syncthreads();
    if (tid == 0) {
        atomicAdd(acc, (double)(wsum[0] + wsum[1] + wsum[2] + wsum[3]));
        __threadfence();
        const unsigned old = atomicAdd(cnt, 1u);
        if (old == gridDim.x - 1) {
            const double t = atomicAdd(acc, 0.0);   // coherent read of final sum
            out[0] = 1.0f - (float)(t * (1.0 / (double)((size_t)NIMG * HH * WW)));
        }
    }
}

extern "C" void kernel_launch(void* const* d_in, const int* in_sizes, int n_in,
                              void* d_out, int out_size, void* d_ws, size_t ws_size,
                              hipStream_t stream) {
    const float* I = (const float*)d_in[0];
    const float* J = (const float*)d_in[1];
    float* out = (float*)d_out;
    double* acc = (double*)d_ws;
    unsigned* cnt = (unsigned*)((char*)d_ws + 8);

    hipMemsetAsync(d_ws, 0, 16, stream);
    // 512 blocks = 16 images x 32 strips of 16 rows; 4 waves/block
    // = exactly 2 blocks/CU (64 KB LDS each -> 2 resident)
    ncc_main<<<512, 256, 0, stream>>>(I, J, acc, cnt, out);
}

// Round 9
// 32.990 us; speedup vs baseline: 2.9069x; 1.0520x over previous
//
#include <hip/hip_runtime.h>

#define HH 512
#define WW 512
#define NIMG 16
#define EPSF 1e-5f
#define INV81 (1.0f / 81.0f)

// Block = 8 waves (512 thr), one (image, 16-row strip). Same 64KB/16-slot
// LDS ring as R8 (each global row loaded once per block) but DOUBLE the
// waves per block at constant LDS: 2 blocks/CU x 8 waves = 4 waves/SIMD
// (2x R8) to cover ds_read latency and barriers. 2 steps x 8 rows, one
// output row per wave per step; step-0 prefetch rows +12..+19 into regs
// during compute, ds_write after barrier into slots of dead rows -4..+3.
__global__ __launch_bounds__(512, 4) void ncc_main(const float* __restrict__ Iin,
                                                   const float* __restrict__ Jin,
                                                   double* __restrict__ acc,
                                                   unsigned* __restrict__ cnt,
                                                   float* __restrict__ out) {
    __shared__ float ring[16][2][512];   // 64 KB: [slot][img][col]
    __shared__ float wsum[8];

    const int tid  = threadIdx.x;
    const int lane = tid & 63;
    const int w    = tid >> 6;           // wave id 0..7
    const int bid  = blockIdx.x;
    const int n    = bid >> 5;           // image (32 strips each)
    const int y0   = (bid & 31) << 4;    // strip base output row
    const int c0   = lane << 3;          // 8 cols per lane

    const float* Ib = Iin + (size_t)n * (HH * WW);
    const float* Jb = Jin + (size_t)n * (HH * WW);

    auto gload = [&](int r, float (&a)[8], float (&b)[8]) {
        if (r >= 0 && r < HH) {           // wave-uniform
            const float4* pI = (const float4*)(Ib + (size_t)r * WW + c0);
            const float4* pJ = (const float4*)(Jb + (size_t)r * WW + c0);
            float4 aL = pI[0], aH = pI[1], bL = pJ[0], bH = pJ[1];
            a[0]=aL.x; a[1]=aL.y; a[2]=aL.z; a[3]=aL.w; a[4]=aH.x; a[5]=aH.y; a[6]=aH.z; a[7]=aH.w;
            b[0]=bL.x; b[1]=bL.y; b[2]=bL.z; b[3]=bL.w; b[4]=bH.x; b[5]=bH.y; b[6]=bH.z; b[7]=bH.w;
        } else {
            #pragma unroll
            for (int c = 0; c < 8; ++c) { a[c] = 0.f; b[c] = 0.f; }
        }
    };
    auto swrite = [&](int r, const float (&a)[8], const float (&b)[8]) {
        const int sl = (r + 16) & 15;
        float4* dI = (float4*)&ring[sl][0][c0];
        float4* dJ = (float4*)&ring[sl][1][c0];
        dI[0] = make_float4(a[0], a[1], a[2], a[3]);
        dI[1] = make_float4(a[4], a[5], a[6], a[7]);
        dJ[0] = make_float4(b[0], b[1], b[2], b[3]);
        dJ[1] = make_float4(b[4], b[5], b[6], b[7]);
    };

    // Prologue: 16 rows (y0-4 .. y0+11), 2 per wave, independent loads.
    {
        float a0[8], b0[8], a1[8], b1[8];
        gload(y0 - 4 + w, a0, b0);
        gload(y0 + 4 + w, a1, b1);
        swrite(y0 - 4 + w, a0, b0);
        swrite(y0 + 4 + w, a1, b1);
    }
    __syncthreads();

    const bool L0  = (lane == 0);
    const bool L63 = (lane == 63);

    auto hbox = [&](const float (&C)[8], float (&B)[8]) {
        float H[16];
        #pragma unroll
        for (int k = 0; k < 4; ++k) {
            float l = __shfl_up(C[4 + k], 1);
            H[k] = L0 ? 0.f : l;
        }
        #pragma unroll
        for (int k = 0; k < 8; ++k) H[4 + k] = C[k];
        #pragma unroll
        for (int k = 0; k < 4; ++k) {
            float r = __shfl_down(C[k], 1);
            H[12 + k] = L63 ? 0.f : r;
        }
        float s = ((H[0] + H[1]) + (H[2] + H[3])) + ((H[4] + H[5]) + (H[6] + H[7])) + H[8];
        B[0] = s;
        #pragma unroll
        for (int i = 1; i < 8; ++i) { s += H[i + 8] - H[i - 1]; B[i] = s; }
    };

    float local = 0.f;

    // Compute one output row R: 9-row vertical window sums from LDS,
    // then horizontal 9-box + cc. Row-by-row accumulate (low live-set).
    auto dorow = [&](int R) {
        float SI[8], SJ[8], SI2[8], SJ2[8], SIJ[8];
        #pragma unroll
        for (int c = 0; c < 8; ++c) { SI[c]=0.f; SJ[c]=0.f; SI2[c]=0.f; SJ2[c]=0.f; SIJ[c]=0.f; }
        #pragma unroll
        for (int k = 0; k < 9; ++k) {
            const int sl = (R - 4 + k + 16) & 15;
            const float4* rI = (const float4*)&ring[sl][0][c0];
            const float4* rJ = (const float4*)&ring[sl][1][c0];
            float4 i0 = rI[0], i1 = rI[1], j0 = rJ[0], j1 = rJ[1];
            float ai[8] = {i0.x, i0.y, i0.z, i0.w, i1.x, i1.y, i1.z, i1.w};
            float bj[8] = {j0.x, j0.y, j0.z, j0.w, j1.x, j1.y, j1.z, j1.w};
            #pragma unroll
            for (int c = 0; c < 8; ++c) {
                SI[c] += ai[c];  SJ[c] += bj[c];
                SI2[c] = fmaf(ai[c], ai[c], SI2[c]);
                SJ2[c] = fmaf(bj[c], bj[c], SJ2[c]);
                SIJ[c] = fmaf(ai[c], bj[c], SIJ[c]);
            }
        }
        float BI[8], BJ[8], BI2[8], BJ2[8], BIJ[8];
        hbox(SI, BI); hbox(SJ, BJ); hbox(SI2, BI2); hbox(SJ2, BJ2); hbox(SIJ, BIJ);
        #pragma unroll
        for (int c = 0; c < 8; ++c) {
            const float tI = BI[c] * INV81;
            const float tJ = BJ[c] * INV81;
            const float cross = fmaf(-tI, BJ[c], BIJ[c]);
            const float Iv    = fmaf(-tI, BI[c], BI2[c]);
            const float Jv    = fmaf(-tJ, BJ[c], BJ2[c]);
            const float den   = fmaf(Iv, Jv, EPSF);
            local = fmaf(cross * cross, __builtin_amdgcn_rcpf(den), local);
        }
    };

    // Step 0: rows y0 .. y0+7 (windows y0-4 .. y0+11, all resident).
    {
        float na[8], nb[8];
        gload(y0 + 12 + w, na, nb);       // prefetch rows +12..+19 (regs)
        dorow(y0 + w);
        __syncthreads();                   // all step-0 reads done
        swrite(y0 + 12 + w, na, nb);       // overwrite dead slots (-4..+3)
        __syncthreads();                   // rows +12..+19 visible
    }
    // Step 1: rows y0+8 .. y0+15 (windows y0+4 .. y0+19, all resident).
    dorow(y0 + 8 + w);

    // wave reduction, block reduction, one atomic per block; last block finalizes
    #pragma unroll
    for (int off = 32; off > 0; off >>= 1) local += __shfl_down(local, off);
    if (lane == 0) wsum[w] = local;
    __syncthreads();
    if (tid == 0) {
        float b = 0.f;
        #pragma unroll
        for (int k = 0; k < 8; ++k) b += wsum[k];
        atomicAdd(acc, (double)b);
        __threadfence();
        const unsigned old = atomicAdd(cnt, 1u);
        if (old == gridDim.x - 1) {
            const double t = atomicAdd(acc, 0.0);   // coherent read of final sum
            out[0] = 1.0f - (float)(t * (1.0 / (double)((size_t)NIMG * HH * WW)));
        }
    }
}

extern "C" void kernel_launch(void* const* d_in, const int* in_sizes, int n_in,
                              void* d_out, int out_size, void* d_ws, size_t ws_size,
                              hipStream_t stream) {
    const float* I = (const float*)d_in[0];
    const float* J = (const float*)d_in[1];
    float* out = (float*)d_out;
    double* acc = (double*)d_ws;
    unsigned* cnt = (unsigned*)((char*)d_ws + 8);

    hipMemsetAsync(d_ws, 0, 16, stream);
    // 512 blocks = 16 images x 32 strips of 16 rows; 8 waves/block
    // = exactly 2 blocks/CU (64 KB LDS) -> 16 waves/CU = 4 waves/SIMD
    ncc_main<<<512, 512, 0, stream>>>(I, J, acc, cnt, out);
}

// Round 10
// 31.149 us; speedup vs baseline: 3.0788x; 1.0591x over previous
//
#include <hip/hip_runtime.h>

#define HH 512
#define WW 512
#define NIMG 16
#define EPSF 1e-5f
#define INV81 (1.0f / 81.0f)

// Block = 8 waves (512 thr), one (image, 16-row strip), 64KB/16-slot LDS
// ring of raw rows (each global row loaded once per block). Round-10
// changes vs R9: (1) XCD-aware bid swizzle -- HW assigns block b to XCD
// b%8, so map b%8 -> image pair (2 images = 4MB = one XCD's L2): all halo
// re-reads become L2 hits instead of independent HBM misses. (2) All 3
// per-wave global row-loads issued as one 12x dwordx4 burst in the
// prologue (more bytes in flight during the cold HBM stream).
__global__ __launch_bounds__(512, 4) void ncc_main(const float* __restrict__ Iin,
                                                   const float* __restrict__ Jin,
                                                   double* __restrict__ acc,
                                                   unsigned* __restrict__ cnt,
                                                   float* __restrict__ out) {
    __shared__ float ring[16][2][512];   // 64 KB: [slot][img][col]
    __shared__ float wsum[8];

    const int tid  = threadIdx.x;
    const int lane = tid & 63;
    const int w    = tid >> 6;           // wave id 0..7
    // XCD swizzle: xcd = bid&7 (HW round-robin); each XCD gets 2 images.
    const int xcd  = blockIdx.x & 7;
    const int idx  = blockIdx.x >> 3;    // 0..63 within XCD
    const int n    = (xcd << 1) | (idx >> 5);   // image
    const int y0   = (idx & 31) << 4;           // strip base output row
    const int c0   = lane << 3;          // 8 cols per lane

    const float* Ib = Iin + (size_t)n * (HH * WW);
    const float* Jb = Jin + (size_t)n * (HH * WW);

    auto gload = [&](int r, float (&a)[8], float (&b)[8]) {
        if (r >= 0 && r < HH) {           // wave-uniform
            const float4* pI = (const float4*)(Ib + (size_t)r * WW + c0);
            const float4* pJ = (const float4*)(Jb + (size_t)r * WW + c0);
            float4 aL = pI[0], aH = pI[1], bL = pJ[0], bH = pJ[1];
            a[0]=aL.x; a[1]=aL.y; a[2]=aL.z; a[3]=aL.w; a[4]=aH.x; a[5]=aH.y; a[6]=aH.z; a[7]=aH.w;
            b[0]=bL.x; b[1]=bL.y; b[2]=bL.z; b[3]=bL.w; b[4]=bH.x; b[5]=bH.y; b[6]=bH.z; b[7]=bH.w;
        } else {
            #pragma unroll
            for (int c = 0; c < 8; ++c) { a[c] = 0.f; b[c] = 0.f; }
        }
    };
    auto swrite = [&](int r, const float (&a)[8], const float (&b)[8]) {
        const int sl = (r + 16) & 15;
        float4* dI = (float4*)&ring[sl][0][c0];
        float4* dJ = (float4*)&ring[sl][1][c0];
        dI[0] = make_float4(a[0], a[1], a[2], a[3]);
        dI[1] = make_float4(a[4], a[5], a[6], a[7]);
        dJ[0] = make_float4(b[0], b[1], b[2], b[3]);
        dJ[1] = make_float4(b[4], b[5], b[6], b[7]);
    };

    // Prologue burst: all 3 rows this wave owns (y0-4+w, y0+4+w, y0+12+w)
    // issued back-to-back (12 dwordx4 in flight) before any dependent use.
    float na[8], nb[8];                   // row y0+12+w, held across step 0
    {
        float a0[8], b0[8], a1[8], b1[8];
        gload(y0 - 4 + w, a0, b0);
        gload(y0 + 4 + w, a1, b1);
        gload(y0 + 12 + w, na, nb);
        swrite(y0 - 4 + w, a0, b0);
        swrite(y0 + 4 + w, a1, b1);
    }
    __syncthreads();

    const bool L0  = (lane == 0);
    const bool L63 = (lane == 63);

    auto hbox = [&](const float (&C)[8], float (&B)[8]) {
        float H[16];
        #pragma unroll
        for (int k = 0; k < 4; ++k) {
            float l = __shfl_up(C[4 + k], 1);
            H[k] = L0 ? 0.f : l;
        }
        #pragma unroll
        for (int k = 0; k < 8; ++k) H[4 + k] = C[k];
        #pragma unroll
        for (int k = 0; k < 4; ++k) {
            float r = __shfl_down(C[k], 1);
            H[12 + k] = L63 ? 0.f : r;
        }
        float s = ((H[0] + H[1]) + (H[2] + H[3])) + ((H[4] + H[5]) + (H[6] + H[7])) + H[8];
        B[0] = s;
        #pragma unroll
        for (int i = 1; i < 8; ++i) { s += H[i + 8] - H[i - 1]; B[i] = s; }
    };

    float local = 0.f;

    // One output row R: 9-row vertical window sums from LDS, then
    // horizontal 9-box + cc. Row-by-row accumulate (low live-set).
    auto dorow = [&](int R) {
        float SI[8], SJ[8], SI2[8], SJ2[8], SIJ[8];
        #pragma unroll
        for (int c = 0; c < 8; ++c) { SI[c]=0.f; SJ[c]=0.f; SI2[c]=0.f; SJ2[c]=0.f; SIJ[c]=0.f; }
        #pragma unroll
        for (int k = 0; k < 9; ++k) {
            const int sl = (R - 4 + k + 16) & 15;
            const float4* rI = (const float4*)&ring[sl][0][c0];
            const float4* rJ = (const float4*)&ring[sl][1][c0];
            float4 i0 = rI[0], i1 = rI[1], j0 = rJ[0], j1 = rJ[1];
            float ai[8] = {i0.x, i0.y, i0.z, i0.w, i1.x, i1.y, i1.z, i1.w};
            float bj[8] = {j0.x, j0.y, j0.z, j0.w, j1.x, j1.y, j1.z, j1.w};
            #pragma unroll
            for (int c = 0; c < 8; ++c) {
                SI[c] += ai[c];  SJ[c] += bj[c];
                SI2[c] = fmaf(ai[c], ai[c], SI2[c]);
                SJ2[c] = fmaf(bj[c], bj[c], SJ2[c]);
                SIJ[c] = fmaf(ai[c], bj[c], SIJ[c]);
            }
        }
        float BI[8], BJ[8], BI2[8], BJ2[8], BIJ[8];
        hbox(SI, BI); hbox(SJ, BJ); hbox(SI2, BI2); hbox(SJ2, BJ2); hbox(SIJ, BIJ);
        #pragma unroll
        for (int c = 0; c < 8; ++c) {
            const float tI = BI[c] * INV81;
            const float tJ = BJ[c] * INV81;
            const float cross = fmaf(-tI, BJ[c], BIJ[c]);
            const float Iv    = fmaf(-tI, BI[c], BI2[c]);
            const float Jv    = fmaf(-tJ, BJ[c], BJ2[c]);
            const float den   = fmaf(Iv, Jv, EPSF);
            local = fmaf(cross * cross, __builtin_amdgcn_rcpf(den), local);
        }
    };

    // Step 0: rows y0 .. y0+7 (windows y0-4 .. y0+11, all resident).
    dorow(y0 + w);
    __syncthreads();                      // all step-0 reads done
    swrite(y0 + 12 + w, na, nb);          // overwrite dead slots (-4..+3)
    __syncthreads();                      // rows +12..+19 visible
    // Step 1: rows y0+8 .. y0+15 (windows y0+4 .. y0+19, all resident).
    dorow(y0 + 8 + w);

    // wave reduction, block reduction, one atomic per block; last block finalizes
    #pragma unroll
    for (int off = 32; off > 0; off >>= 1) local += __shfl_down(local, off);
    if (lane == 0) wsum[w] = local;
    __syncthreads();
    if (tid == 0) {
        float b = 0.f;
        #pragma unroll
        for (int k = 0; k < 8; ++k) b += wsum[k];
        atomicAdd(acc, (double)b);
        __threadfence();
        const unsigned old = atomicAdd(cnt, 1u);
        if (old == gridDim.x - 1) {
            const double t = atomicAdd(acc, 0.0);   // coherent read of final sum
            out[0] = 1.0f - (float)(t * (1.0 / (double)((size_t)NIMG * HH * WW)));
        }
    }
}

extern "C" void kernel_launch(void* const* d_in, const int* in_sizes, int n_in,
                              void* d_out, int out_size, void* d_ws, size_t ws_size,
                              hipStream_t stream) {
    const float* I = (const float*)d_in[0];
    const float* J = (const float*)d_in[1];
    float* out = (float*)d_out;
    double* acc = (double*)d_ws;
    unsigned* cnt = (unsigned*)((char*)d_ws + 8);

    hipMemsetAsync(d_ws, 0, 16, stream);
    // 512 blocks = 16 images x 32 strips of 16 rows; 8 waves/block.
    // bid&7 = XCD (HW round-robin) -> each XCD owns 2 images (4MB = L2).
    ncc_main<<<512, 512, 0, stream>>>(I, J, acc, cnt, out);
}

// Round 11
// 29.225 us; speedup vs baseline: 3.2814x; 1.0658x over previous
//
#include <hip/hip_runtime.h>

#define HH 512
#define WW 512
#define NIMG 16
#define EPSF 1e-5f
#define INV81 (1.0f / 81.0f)

// lane l receives lane l-1's value; lane 0 -> 0  (wave_shr:1, bound_ctrl=1)
__device__ __forceinline__ float dpp_shr1(float x) {
    return __int_as_float(__builtin_amdgcn_update_dpp(
        0, __float_as_int(x), 0x138, 0xF, 0xF, true));
}
// lane l receives lane l+1's value; lane 63 -> 0  (wave_shl:1, bound_ctrl=1)
__device__ __forceinline__ float dpp_shl1(float x) {
    return __int_as_float(__builtin_amdgcn_update_dpp(
        0, __float_as_int(x), 0x130, 0xF, 0xF, true));
}

// Block = 8 waves (512 thr), one (image, 16-row strip), 64KB/16-slot LDS
// ring (each global row loaded once per block). Round-11 vs R10:
// (1) CONFLICT-FREE LDS LAYOUT: row-img stored as A[lane] (cols 8l..8l+3)
//     at byte 16*lane and B[lane] (cols 8l+4..8l+7) at byte 1024+16*lane.
//     All ds_read/write_b128 are lane-stride-16B -> 32 banks covered, 8cy,
//     zero conflicts (old layout: stride 32B -> half banks -> ~2x).
// (2) hbox halos via DPP wave_shr:1/wave_shl:1 (VALU pipe, auto zero-fill)
//     instead of __shfl (ds_bpermute on the congested LDS pipe).
__global__ __launch_bounds__(512, 4) void ncc_main(const float* __restrict__ Iin,
                                                   const float* __restrict__ Jin,
                                                   double* __restrict__ acc,
                                                   unsigned* __restrict__ cnt,
                                                   float* __restrict__ out) {
    __shared__ float4 ring4[16][2][128];  // 64 KB: [slot][img][A(0..63)|B(64..127)]
    __shared__ float wsum[8];

    const int tid  = threadIdx.x;
    const int lane = tid & 63;
    const int w    = tid >> 6;           // wave id 0..7
    // XCD swizzle: xcd = bid&7 (HW round-robin); each XCD gets 2 images.
    const int xcd  = blockIdx.x & 7;
    const int idx  = blockIdx.x >> 3;    // 0..63 within XCD
    const int n    = (xcd << 1) | (idx >> 5);   // image
    const int y0   = (idx & 31) << 4;           // strip base output row
    const int c0   = lane << 3;          // 8 cols per lane (global addressing)

    const float* Ib = Iin + (size_t)n * (HH * WW);
    const float* Jb = Jin + (size_t)n * (HH * WW);

    auto gload = [&](int r, float4& a0, float4& a1, float4& b0, float4& b1) {
        if (r >= 0 && r < HH) {           // wave-uniform
            const float4* pI = (const float4*)(Ib + (size_t)r * WW + c0);
            const float4* pJ = (const float4*)(Jb + (size_t)r * WW + c0);
            a0 = pI[0]; a1 = pI[1]; b0 = pJ[0]; b1 = pJ[1];
        } else {
            a0 = a1 = b0 = b1 = make_float4(0.f, 0.f, 0.f, 0.f);
        }
    };
    auto swrite = [&](int r, const float4& a0, const float4& a1,
                             const float4& b0, const float4& b1) {
        const int sl = (r + 16) & 15;
        ring4[sl][0][lane]      = a0;     // A region: byte 16*lane
        ring4[sl][0][64 + lane] = a1;     // B region: byte 1024+16*lane
        ring4[sl][1][lane]      = b0;
        ring4[sl][1][64 + lane] = b1;
    };

    // Prologue burst: all 3 rows this wave owns, issued before any use.
    float4 na0, na1, nb0, nb1;            // row y0+12+w, held across step 0
    {
        float4 p0, p1, q0, q1, r0, r1, s0, s1;
        gload(y0 - 4 + w, p0, p1, q0, q1);
        gload(y0 + 4 + w, r0, r1, s0, s1);
        gload(y0 + 12 + w, na0, na1, nb0, nb1);
        swrite(y0 - 4 + w, p0, p1, q0, q1);
        swrite(y0 + 4 + w, r0, r1, s0, s1);
    }
    __syncthreads();

    // horizontal 9-box over per-col vertical sums; halos via DPP (VALU pipe)
    auto hbox = [&](const float (&C)[8], float (&B)[8]) {
        float H[16];
        #pragma unroll
        for (int k = 0; k < 4; ++k) H[k] = dpp_shr1(C[4 + k]);   // lane-1 cols, lane0->0
        #pragma unroll
        for (int k = 0; k < 8; ++k) H[4 + k] = C[k];
        #pragma unroll
        for (int k = 0; k < 4; ++k) H[12 + k] = dpp_shl1(C[k]);  // lane+1 cols, lane63->0
        float s = ((H[0] + H[1]) + (H[2] + H[3])) + ((H[4] + H[5]) + (H[6] + H[7])) + H[8];
        B[0] = s;
        #pragma unroll
        for (int i = 1; i < 8; ++i) { s += H[i + 8] - H[i - 1]; B[i] = s; }
    };

    float local = 0.f;

    // One output row R: 9-row vertical window sums from LDS (conflict-free
    // b128 reads), then horizontal 9-box + cc. Row-by-row accumulate.
    auto dorow = [&](int R) {
        float SI[8], SJ[8], SI2[8], SJ2[8], SIJ[8];
        #pragma unroll
        for (int c = 0; c < 8; ++c) { SI[c]=0.f; SJ[c]=0.f; SI2[c]=0.f; SJ2[c]=0.f; SIJ[c]=0.f; }
        #pragma unroll
        for (int k = 0; k < 9; ++k) {
            const int sl = (R - 4 + k + 16) & 15;
            const float4 i0 = ring4[sl][0][lane];
            const float4 i1 = ring4[sl][0][64 + lane];
            const float4 j0 = ring4[sl][1][lane];
            const float4 j1 = ring4[sl][1][64 + lane];
            const float ai[8] = {i0.x, i0.y, i0.z, i0.w, i1.x, i1.y, i1.z, i1.w};
            const float bj[8] = {j0.x, j0.y, j0.z, j0.w, j1.x, j1.y, j1.z, j1.w};
            #pragma unroll
            for (int c = 0; c < 8; ++c) {
                SI[c] += ai[c];  SJ[c] += bj[c];
                SI2[c] = fmaf(ai[c], ai[c], SI2[c]);
                SJ2[c] = fmaf(bj[c], bj[c], SJ2[c]);
                SIJ[c] = fmaf(ai[c], bj[c], SIJ[c]);
            }
        }
        float BI[8], BJ[8], BI2[8], BJ2[8], BIJ[8];
        hbox(SI, BI); hbox(SJ, BJ); hbox(SI2, BI2); hbox(SJ2, BJ2); hbox(SIJ, BIJ);
        #pragma unroll
        for (int c = 0; c < 8; ++c) {
            const float tI = BI[c] * INV81;
            const float tJ = BJ[c] * INV81;
            const float cross = fmaf(-tI, BJ[c], BIJ[c]);
            const float Iv    = fmaf(-tI, BI[c], BI2[c]);
            const float Jv    = fmaf(-tJ, BJ[c], BJ2[c]);
            const float den   = fmaf(Iv, Jv, EPSF);
            local = fmaf(cross * cross, __builtin_amdgcn_rcpf(den), local);
        }
    };

    // Step 0: rows y0 .. y0+7 (windows y0-4 .. y0+11, all resident).
    dorow(y0 + w);
    __syncthreads();                      // all step-0 reads done
    swrite(y0 + 12 + w, na0, na1, nb0, nb1);  // overwrite dead slots (-4..+3)
    __syncthreads();                      // rows +12..+19 visible
    // Step 1: rows y0+8 .. y0+15 (windows y0+4 .. y0+19, all resident).
    dorow(y0 + 8 + w);

    // wave reduction, block reduction, one atomic per block; last block finalizes
    #pragma unroll
    for (int off = 32; off > 0; off >>= 1) local += __shfl_down(local, off);
    if (lane == 0) wsum[w] = local;
    __syncthreads();
    if (tid == 0) {
        float b = 0.f;
        #pragma unroll
        for (int k = 0; k < 8; ++k) b += wsum[k];
        atomicAdd(acc, (double)b);
        __threadfence();
        const unsigned old = atomicAdd(cnt, 1u);
        if (old == gridDim.x - 1) {
            const double t = atomicAdd(acc, 0.0);   // coherent read of final sum
            out[0] = 1.0f - (float)(t * (1.0 / (double)((size_t)NIMG * HH * WW)));
        }
    }
}

extern "C" void kernel_launch(void* const* d_in, const int* in_sizes, int n_in,
                              void* d_out, int out_size, void* d_ws, size_t ws_size,
                              hipStream_t stream) {
    const float* I = (const float*)d_in[0];
    const float* J = (const float*)d_in[1];
    float* out = (float*)d_out;
    double* acc = (double*)d_ws;
    unsigned* cnt = (unsigned*)((char*)d_ws + 8);

    hipMemsetAsync(d_ws, 0, 16, stream);
    // 512 blocks = 16 images x 32 strips of 16 rows; 8 waves/block.
    // bid&7 = XCD (HW round-robin) -> each XCD owns 2 images (4MB = L2).
    ncc_main<<<512, 512, 0, stream>>>(I, J, acc, cnt, out);
}